// Round 11
// baseline (2222.498 us; speedup 1.0000x reference)
//
#include <hip/hip_runtime.h>

// DustRiskFormer: B=8 T=48 N=512 F=16 S=12 H=128 NH=8 HZ=6 NC=3
// All float tensors f32; adj int32.
// Outputs (f32, concat flat): reg[8,512,6] risk[8,512,6,3] warn[8,512,6]
//                             t_attn[4096,48,48] alpha[8,512,512]
// R7 insight: t_repr = h[:, -1] -> only ROW 47 of out-proj/LN1/FFN/LN2 matters.
// R8: bf16 q/k/v (LDS 151KB -> 53KB); tatt overlays dead hb; row-47 tail.
// R11 FIX: FFN residual must be LN1 OUTPUT (ln1v), not pre-LN1 h47.
//          R10 run failed (absmax 7e-2) because phase 10 did h47 += ffn;
//          reference is h_final = LN2(ln1(h1+attn) + ffn).

#define B_ 8
#define T_ 48
#define N_ 512
#define F_ 16
#define S_ 12
#define H_ 128
#define NH_ 8
#define HD_ 16

typedef unsigned short ushort_t;
typedef short bf16x8 __attribute__((ext_vector_type(8)));
typedef float f32x4 __attribute__((ext_vector_type(4)));

__device__ __forceinline__ ushort_t f2us(float f) {
  union { float f; unsigned int i; } v; v.f = f;
  unsigned int r = v.i + 0x7FFFu + ((v.i >> 16) & 1u);   // RNE
  return (ushort_t)(r >> 16);
}
__device__ __forceinline__ unsigned int pk2(float a, float b) {
  return (unsigned int)f2us(a) | ((unsigned int)f2us(b) << 16);
}
__device__ __forceinline__ float lo2f(unsigned int u) {
  union { unsigned int i; float f; } v; v.i = u << 16; return v.f;
}
__device__ __forceinline__ float hi2f(unsigned int u) {
  union { unsigned int i; float f; } v; v.i = u & 0xffff0000u; return v.f;
}
__device__ __forceinline__ float us2f(ushort_t u) {
  union { unsigned int i; float f; } v; v.i = ((unsigned int)u) << 16; return v.f;
}
__device__ __forceinline__ float dot128(const float* __restrict__ a,
                                        const float* __restrict__ w) {
  float s = 0.f;
  #pragma unroll 8
  for (int c = 0; c < 32; ++c) {
    float4 av = *(const float4*)(a + 4 * c);
    float4 wv = *(const float4*)(w + 4 * c);
    s += av.x * wv.x + av.y * wv.y + av.z * wv.z + av.w * wv.w;
  }
  return s;
}

#define MFMA16(a, b, c) __builtin_amdgcn_mfma_f32_16x16x32_bf16(a, b, c, 0, 0, 0)

// -------- weight pre-pack (in_w only): f32 -> bf16, MFMA A-fragment order ----
// lane l holds row mt*16+(l&15), k = ks*32+(l>>4)*8+j ; packed[((mt*4+ks)*64+l)*8+j]
__global__ __launch_bounds__(256)
void k_prep(const float* __restrict__ inw, ushort_t* __restrict__ wp)
{
  int i = blockIdx.x * 256 + threadIdx.x;     // 49152 total
  int j    = i & 7;
  int lane = (i >> 3) & 63;
  int tile = i >> 9;
  int mt   = tile >> 2, ks = tile & 3;
  int row  = mt * 16 + (lane & 15);
  int k    = ks * 32 + ((lane >> 4) & 3) * 8 + j;
  wp[i] = f2us(inw[(size_t)row * H_ + k]);
}

struct alignas(16) SmemA {
  union { ushort_t hb[T_][H_]; float tatt[T_][49]; } hu;   // 12.3KB (disjoint lifetimes)
  union { struct { ushort_t q[T_][H_], k[T_][H_], v[T_][H_]; } a;
          float xs[T_][F_]; } u;                            // 36.9KB
  float p47[NH_][T_];   // head-probs for row 47 (PV input)
  float h47[H_];        // residual row 47
  float attn47[H_];
  float ln1v[H_];
  float g47[2 * H_];
};                      // ~53.2KB -> 2-3 blocks/CU

__global__ __launch_bounds__(512, 4)
void k_seq(const float* __restrict__ x,
           const float* __restrict__ pw,  const float* __restrict__ pb,
           const float* __restrict__ in_b,
           const float* __restrict__ ow,  const float* __restrict__ ob,
           const float* __restrict__ l1g, const float* __restrict__ l1b,
           const float* __restrict__ w1,  const float* __restrict__ b1,
           const float* __restrict__ w2,  const float* __restrict__ b2,
           const float* __restrict__ l2g, const float* __restrict__ l2b,
           const ushort_t* __restrict__ wpk,
           float* __restrict__ out_tatt, float* __restrict__ t_repr)
{
  __shared__ SmemA sm;
  const int seq = blockIdx.x;
  const int b = seq >> 9, n = seq & (N_ - 1);
  const int tid = threadIdx.x;
  const int wv = tid >> 6, ln = tid & 63;
  const int lg = ln >> 4, lr = ln & 15;

  // ---- 1. load x[b,:,n,:] ----
  for (int i = tid; i < T_ * F_; i += 512) {
    int t = i >> 4, f = i & 15;
    sm.u.xs[t][f] = x[((size_t)(b * T_ + t) * N_ + n) * F_ + f];
  }
  __syncthreads();

  // ---- 2. proj: hb = bf16(xs @ pw^T + pb), swizzled; row 47 also f32 ----
  for (int i = tid; i < T_ * 64; i += 512) {     // 6 iters
    int t = i >> 6, hp = (i & 63) * 2;
    float s0 = pb[hp], s1 = pb[hp + 1];
    const float* w0 = pw + hp * F_;
    const float* w1r = w0 + F_;
    #pragma unroll
    for (int f = 0; f < F_; ++f) {
      float xv = sm.u.xs[t][f];
      s0 += xv * w0[f]; s1 += xv * w1r[f];
    }
    *(unsigned int*)((char*)sm.hu.hb + ((t * 256 + hp * 2) ^ ((t & 7) << 4))) = pk2(s0, s1);
    if (t == T_ - 1) { sm.h47[hp] = s0; sm.h47[hp + 1] = s1; }
  }
  __syncthreads();

  // ---- 3. qkv MFMA: [384 out] x [48 t], K=128; out -> bf16 q/k/v swizzled ----
  {
    f32x4 acc[3][3];
    #pragma unroll
    for (int i = 0; i < 3; ++i)
      #pragma unroll
      for (int j = 0; j < 3; ++j) acc[i][j] = (f32x4){0.f, 0.f, 0.f, 0.f};
    #pragma unroll
    for (int ks = 0; ks < 4; ++ks) {
      bf16x8 Af[3], Bf[3];
      #pragma unroll
      for (int i = 0; i < 3; ++i) {
        int mt = wv * 3 + i;
        Af[i] = *(const bf16x8*)(wpk + (size_t)((mt * 4 + ks) * 64 + ln) * 8);
        int row = i * 16 + lr;
        Bf[i] = *(const bf16x8*)((const char*)sm.hu.hb +
                 ((row * 256 + ks * 64 + lg * 16) ^ ((row & 7) << 4)));
      }
      #pragma unroll
      for (int i = 0; i < 3; ++i)
        #pragma unroll
        for (int j = 0; j < 3; ++j) acc[i][j] = MFMA16(Af[i], Bf[j], acc[i][j]);
    }
    #pragma unroll
    for (int i = 0; i < 3; ++i) {
      int hh0 = (wv * 3 + i) * 16 + lg * 4;       // 0..383
      float4 bias = *(const float4*)(in_b + hh0);
      #pragma unroll
      for (int j = 0; j < 3; ++j) {
        int t = j * 16 + lr;
        float o0 = acc[i][j].x + bias.x, o1 = acc[i][j].y + bias.y;
        float o2 = acc[i][j].z + bias.z, o3 = acc[i][j].w + bias.w;
        ushort_t* buf; int hl;
        if (hh0 < 128)      { buf = &sm.u.a.q[0][0]; hl = hh0;
                              o0 *= 0.25f; o1 *= 0.25f; o2 *= 0.25f; o3 *= 0.25f; }
        else if (hh0 < 256) { buf = &sm.u.a.k[0][0]; hl = hh0 - 128; }
        else                { buf = &sm.u.a.v[0][0]; hl = hh0 - 256; }
        *(uint2*)((char*)buf + ((t * 256 + hl * 2) ^ ((t & 7) << 4))) =
            make_uint2(pk2(o0, o1), pk2(o2, o3));
      }
    }
  }
  __syncthreads();

  // ---- 4. zero tatt (hb now dead) ----
  for (int i = tid; i < T_ * 49; i += 512) (&sm.hu.tatt[0][0])[i] = 0.f;
  __syncthreads();

  // ---- 5. attention scores: wave = head, lane r<48 = query row ----
  if (ln < T_) {
    const int r = ln;
    const char* qb = (const char*)sm.u.a.q;
    const char* kb = (const char*)sm.u.a.k;
    uint4 qa = *(const uint4*)(qb + ((r * 256 + wv * 32) ^ ((r & 7) << 4)));
    uint4 qc = *(const uint4*)(qb + ((r * 256 + wv * 32 + 16) ^ ((r & 7) << 4)));
    float qv[16] = { lo2f(qa.x), hi2f(qa.x), lo2f(qa.y), hi2f(qa.y),
                     lo2f(qa.z), hi2f(qa.z), lo2f(qa.w), hi2f(qa.w),
                     lo2f(qc.x), hi2f(qc.x), lo2f(qc.y), hi2f(qc.y),
                     lo2f(qc.z), hi2f(qc.z), lo2f(qc.w), hi2f(qc.w) };
    float sc[T_];
    float m = -1e30f;
    #pragma unroll
    for (int k = 0; k < T_; ++k) {
      uint4 ka = *(const uint4*)(kb + ((k * 256 + wv * 32) ^ ((k & 7) << 4)));
      uint4 kc = *(const uint4*)(kb + ((k * 256 + wv * 32 + 16) ^ ((k & 7) << 4)));
      float s = qv[0] * lo2f(ka.x) + qv[1] * hi2f(ka.x) + qv[2] * lo2f(ka.y) + qv[3] * hi2f(ka.y)
              + qv[4] * lo2f(ka.z) + qv[5] * hi2f(ka.z) + qv[6] * lo2f(ka.w) + qv[7] * hi2f(ka.w)
              + qv[8] * lo2f(kc.x) + qv[9] * hi2f(kc.x) + qv[10] * lo2f(kc.y) + qv[11] * hi2f(kc.y)
              + qv[12] * lo2f(kc.z) + qv[13] * hi2f(kc.z) + qv[14] * lo2f(kc.w) + qv[15] * hi2f(kc.w);
      sc[k] = s; m = fmaxf(m, s);
    }
    float sum = 0.f;
    #pragma unroll
    for (int k = 0; k < T_; ++k) { float p = __expf(sc[k] - m); sc[k] = p; sum += p; }
    float inv = 1.f / sum;
    #pragma unroll
    for (int k = 0; k < T_; ++k) {
      sc[k] *= inv;
      atomicAdd(&sm.hu.tatt[r][k], sc[k] * 0.125f);
    }
    if (r == T_ - 1) {            // stash row-47 probs for PV
      #pragma unroll
      for (int c = 0; c < 12; ++c)
        *(float4*)&sm.p47[wv][4 * c] = make_float4(sc[4 * c], sc[4 * c + 1],
                                                   sc[4 * c + 2], sc[4 * c + 3]);
    }
  }
  __syncthreads();

  // ---- 6. tatt writeout + PV(row 47) -> attn47 ----
  for (int i = tid; i < T_ * T_; i += 512) {
    int r = i / T_, k = i - r * T_;
    out_tatt[(size_t)seq * T_ * T_ + i] = sm.hu.tatt[r][k];
  }
  {
    // 512 thr: head=wv, c=ln>>2, ks=ln&3; 12 k each; shfl-reduce 4 partials
    int c = ln >> 2, ks = ln & 3;
    const char* vb = (const char*)sm.u.a.v;
    float a = 0.f;
    for (int kk = 0; kk < 12; ++kk) {
      int k = ks * 12 + kk;
      float p = sm.p47[wv][k];
      ushort_t vv = *(const ushort_t*)(vb + ((k * 256 + (wv * 16 + c) * 2) ^ ((k & 7) << 4)));
      a += p * us2f(vv);
    }
    a += __shfl_xor(a, 1, 64);
    a += __shfl_xor(a, 2, 64);
    if (ks == 0) sm.attn47[wv * 16 + c] = a;
  }
  __syncthreads();

  // ---- 7. out-proj row 47: h47 += attn47 @ ow^T + ob  (h47 = h1 + attn) ----
  {
    int o = tid >> 2, ks = tid & 3;
    const float* wr = ow + (size_t)o * H_ + ks * 32;
    const float* ar = sm.attn47 + ks * 32;
    float s = 0.f;
    #pragma unroll
    for (int c = 0; c < 8; ++c) {
      float4 av = *(const float4*)(ar + 4 * c);
      float4 wvv = *(const float4*)(wr + 4 * c);
      s += av.x * wvv.x + av.y * wvv.y + av.z * wvv.z + av.w * wvv.w;
    }
    s += __shfl_xor(s, 1, 64);
    s += __shfl_xor(s, 2, 64);
    if (ks == 0) sm.h47[o] += s + ob[o];
  }
  __syncthreads();

  // ---- 8. LN1 row 47 (wave 0) -> ln1v ----
  if (tid < 64) {
    float v0 = sm.h47[2 * tid], v1 = sm.h47[2 * tid + 1];
    float s = v0 + v1;
    #pragma unroll
    for (int off = 32; off; off >>= 1) s += __shfl_xor(s, off, 64);
    float mean = s * (1.f / H_);
    float d0 = v0 - mean, d1 = v1 - mean;
    float q = d0 * d0 + d1 * d1;
    #pragma unroll
    for (int off = 32; off; off >>= 1) q += __shfl_xor(q, off, 64);
    float rstd = rsqrtf(q * (1.f / H_) + 1e-5f);
    sm.ln1v[2 * tid]     = d0 * rstd * l1g[2 * tid]     + l1b[2 * tid];
    sm.ln1v[2 * tid + 1] = d1 * rstd * l1g[2 * tid + 1] + l1b[2 * tid + 1];
  }
  __syncthreads();

  // ---- 9. FFN1 row 47: g47 = gelu(ln1v @ w1^T + b1) ----
  {
    int o = tid >> 1, ks = tid & 1;
    const float* wr = w1 + (size_t)o * H_ + ks * 64;
    const float* ar = sm.ln1v + ks * 64;
    float s = 0.f;
    #pragma unroll
    for (int c = 0; c < 16; ++c) {
      float4 av = *(const float4*)(ar + 4 * c);
      float4 wvv = *(const float4*)(wr + 4 * c);
      s += av.x * wvv.x + av.y * wvv.y + av.z * wvv.z + av.w * wvv.w;
    }
    s += __shfl_xor(s, 1, 64);
    if (ks == 0) {
      float g = s + b1[o];
      sm.g47[o] = 0.5f * g * (1.f + erff(g * 0.70710678118f));
    }
  }
  __syncthreads();

  // ---- 10. FFN2 row 47: h47 = ln1v + g47 @ w2^T + b2  (R11 FIX: rebase on ln1v) ----
  {
    int o = tid >> 2, ks = tid & 3;
    const float* wr = w2 + (size_t)o * 2 * H_ + ks * 64;
    const float* ar = sm.g47 + ks * 64;
    float s = 0.f;
    #pragma unroll
    for (int c = 0; c < 16; ++c) {
      float4 av = *(const float4*)(ar + 4 * c);
      float4 wvv = *(const float4*)(wr + 4 * c);
      s += av.x * wvv.x + av.y * wvv.y + av.z * wvv.z + av.w * wvv.w;
    }
    s += __shfl_xor(s, 1, 64);
    s += __shfl_xor(s, 2, 64);
    if (ks == 0) sm.h47[o] = sm.ln1v[o] + s + b2[o];
  }
  __syncthreads();

  // ---- 11. LN2 row 47 (wave 0) -> t_repr ----
  if (tid < 64) {
    float v0 = sm.h47[2 * tid], v1 = sm.h47[2 * tid + 1];
    float s = v0 + v1;
    #pragma unroll
    for (int off = 32; off; off >>= 1) s += __shfl_xor(s, off, 64);
    float mean = s * (1.f / H_);
    float d0 = v0 - mean, d1 = v1 - mean;
    float q = d0 * d0 + d1 * d1;
    #pragma unroll
    for (int off = 32; off; off >>= 1) q += __shfl_xor(q, off, 64);
    float rstd = rsqrtf(q * (1.f / H_) + 1e-5f);
    t_repr[(size_t)seq * H_ + 2 * tid]     = d0 * rstd * l2g[2 * tid]     + l2b[2 * tid];
    t_repr[(size_t)seq * H_ + 2 * tid + 1] = d1 * rstd * l2g[2 * tid + 1] + l2b[2 * tid + 1];
  }
}

// s_repr[n][hh] = relu(x_static[n] . stat_w[hh] + stat_b[hh])
__global__ __launch_bounds__(256)
void k_static(const float* __restrict__ xst, const float* __restrict__ sw,
              const float* __restrict__ sb, float* __restrict__ s_repr)
{
  int idx = blockIdx.x * 256 + threadIdx.x;   // 512*128
  int n = idx >> 7, hh = idx & 127;
  float s = sb[hh];
  #pragma unroll
  for (int c = 0; c < S_; ++c) s += xst[n * S_ + c] * sw[hh * S_ + c];
  s_repr[idx] = fmaxf(s, 0.f);
}

// gh[b,n,:] = node @ gat_w^T ; ga1/ga2 = gh . a1 / a2
__global__ __launch_bounds__(128)
void k_gatproj(const float* __restrict__ t_repr, const float* __restrict__ s_repr,
               const float* __restrict__ gat_w, const float* __restrict__ gat_a,
               float* __restrict__ gh, float* __restrict__ ga1, float* __restrict__ ga2)
{
  int bi = blockIdx.x;            // b*512+n
  int n = bi & (N_ - 1);
  int hh = threadIdx.x;
  const float* wr = gat_w + hh * 2 * H_;
  float s = dot128(t_repr + (size_t)bi * H_, wr) +
            dot128(s_repr + (size_t)n * H_, wr + H_);
  gh[(size_t)bi * H_ + hh] = s;
  float c1 = s * gat_a[hh];
  float c2 = s * gat_a[H_ + hh];
  #pragma unroll
  for (int off = 32; off; off >>= 1) {
    c1 += __shfl_xor(c1, off, 64);
    c2 += __shfl_xor(c2, off, 64);
  }
  __shared__ float r1[2], r2[2];
  int w = hh >> 6;
  if ((hh & 63) == 0) { r1[w] = c1; r2[w] = c2; }
  __syncthreads();
  if (hh == 0) { ga1[bi] = r1[0] + r1[1]; ga2[bi] = r2[0] + r2[1]; }
}

// per (b,i): e-row -> softmax -> alpha out; g_repr; fused; heads
__global__ __launch_bounds__(256)
void k_gat(const int* __restrict__ adj, const float* __restrict__ gh,
           const float* __restrict__ ga1, const float* __restrict__ ga2,
           const float* __restrict__ t_repr, const float* __restrict__ s_repr,
           const float* __restrict__ fw, const float* __restrict__ fb,
           const float* __restrict__ regw, const float* __restrict__ regb,
           const float* __restrict__ riskw, const float* __restrict__ riskb,
           const float* __restrict__ warnw, const float* __restrict__ warnb,
           float* __restrict__ out_alpha, float* __restrict__ out_reg,
           float* __restrict__ out_risk, float* __restrict__ out_warn)
{
  const int row = blockIdx.x;     // b*512 + i
  const int bb = row >> 9, i = row & (N_ - 1);
  const int tid = threadIdx.x;
  __shared__ float ev[N_];
  alignas(16) __shared__ float av[3 * H_];   // [t_repr row | s_repr row | g_repr]
  __shared__ float part[256];
  alignas(16) __shared__ float fus[H_];
  __shared__ float red[4];

  const float g1 = ga1[row];
  const float* g2 = ga2 + (size_t)bb * N_;
  float lmax = -1e30f;
  for (int j = tid; j < N_; j += 256) {
    float e = g1 + g2[j];
    e = e > 0.f ? e : 0.2f * e;               // leaky_relu(0.2)
    if (adj[i * N_ + j] == 0) e = -1e30f;     // mask
    ev[j] = e; lmax = fmaxf(lmax, e);
  }
  #pragma unroll
  for (int off = 32; off; off >>= 1) lmax = fmaxf(lmax, __shfl_xor(lmax, off, 64));
  if ((tid & 63) == 0) red[tid >> 6] = lmax;
  __syncthreads();
  const float m = fmaxf(fmaxf(red[0], red[1]), fmaxf(red[2], red[3]));
  float lsum = 0.f;
  for (int j = tid; j < N_; j += 256) {
    float p = __expf(ev[j] - m);
    ev[j] = p; lsum += p;
  }
  #pragma unroll
  for (int off = 32; off; off >>= 1) lsum += __shfl_xor(lsum, off, 64);
  __syncthreads();                             // all have read red (max)
  if ((tid & 63) == 0) red[tid >> 6] = lsum;
  __syncthreads();
  const float inv = 1.f / (red[0] + red[1] + red[2] + red[3]);
  for (int j = tid; j < N_; j += 256) {
    float a = ev[j] * inv;
    ev[j] = a;
    out_alpha[(size_t)row * N_ + j] = a;
  }
  // stage av[0:256] = [t_repr row | s_repr row]
  av[tid] = (tid < H_) ? t_repr[(size_t)row * H_ + tid]
                       : s_repr[(size_t)i * H_ + (tid - H_)];
  __syncthreads();

  // g_repr: 256 thr (hh x K-half), then halves reduce
  {
    int hh = tid & 127, half = tid >> 7;
    const float* ghb = gh + ((size_t)bb * N_ + half * 256) * H_ + hh;
    float acc = 0.f;
    for (int j = 0; j < 256; ++j) acc += ev[half * 256 + j] * ghb[(size_t)j * H_];
    part[tid] = acc;
  }
  __syncthreads();
  if (tid < H_) av[2 * H_ + tid] = part[tid] + part[H_ + tid];
  __syncthreads();

  // fused: 256 thr (hh x K-half of 192), then reduce + relu
  {
    int hh = tid & 127, half = tid >> 7;
    const float* wr = fw + (size_t)hh * 3 * H_ + half * 192;
    const float* ar = av + half * 192;
    float s = 0.f;
    #pragma unroll 8
    for (int c = 0; c < 48; ++c) {
      float4 avv = *(const float4*)(ar + 4 * c);
      float4 wvv = *(const float4*)(wr + 4 * c);
      s += avv.x * wvv.x + avv.y * wvv.y + avv.z * wvv.z + avv.w * wvv.w;
    }
    part[tid] = s;
  }
  __syncthreads();
  if (tid < H_) fus[tid] = fmaxf(part[tid] + part[H_ + tid] + fb[tid], 0.f);
  __syncthreads();

  if (tid < 30) {                              // heads: 6 reg, 18 risk, 6 warn
    const float *wp, *bp; float* op; int o;
    if (tid < 6)       { o = tid;      wp = regw  + o * H_; bp = regb  + o; op = out_reg  + (size_t)row * 6  + o; }
    else if (tid < 24) { o = tid - 6;  wp = riskw + o * H_; bp = riskb + o; op = out_risk + (size_t)row * 18 + o; }
    else               { o = tid - 24; wp = warnw + o * H_; bp = warnb + o; op = out_warn + (size_t)row * 6  + o; }
    float s = *bp + dot128(fus, wp);
    *op = s;
  }
}

extern "C" void kernel_launch(void* const* d_in, const int* in_sizes, int n_in,
                              void* d_out, int out_size, void* d_ws, size_t ws_size,
                              hipStream_t stream)
{
  const float* x    = (const float*)d_in[0];
  const float* xst  = (const float*)d_in[1];
  const int*   adj  = (const int*)d_in[2];
  const float* pw   = (const float*)d_in[3];
  const float* pb   = (const float*)d_in[4];
  const float* inw  = (const float*)d_in[5];
  const float* inb  = (const float*)d_in[6];
  const float* ow   = (const float*)d_in[7];
  const float* ob   = (const float*)d_in[8];
  const float* l1g  = (const float*)d_in[9];
  const float* l1b  = (const float*)d_in[10];
  const float* w1   = (const float*)d_in[11];
  const float* b1   = (const float*)d_in[12];
  const float* w2   = (const float*)d_in[13];
  const float* b2   = (const float*)d_in[14];
  const float* l2g  = (const float*)d_in[15];
  const float* l2b  = (const float*)d_in[16];
  const float* stw  = (const float*)d_in[17];
  const float* stb  = (const float*)d_in[18];
  const float* gatw = (const float*)d_in[19];
  const float* gata = (const float*)d_in[20];
  const float* fw   = (const float*)d_in[21];
  const float* fb   = (const float*)d_in[22];
  const float* regw = (const float*)d_in[23];
  const float* regb = (const float*)d_in[24];
  const float* rkw  = (const float*)d_in[25];
  const float* rkb  = (const float*)d_in[26];
  const float* wnw  = (const float*)d_in[27];
  const float* wnb  = (const float*)d_in[28];

  float* out       = (float*)d_out;
  float* out_reg   = out;                 // 24576
  float* out_risk  = out + 24576;         // 73728
  float* out_warn  = out + 98304;         // 24576
  float* out_tatt  = out + 122880;        // 9437184
  float* out_alpha = out + 9560064;       // 2097152

  float* ws     = (float*)d_ws;           // f32 scratch (4,489,216 B total, proven)
  float* t_repr = ws;                     // 4096*128
  float* s_repr = ws + 524288;            // 512*128
  float* gh     = ws + 589824;            // 4096*128  (wpk aliases the front)
  float* ga1    = ws + 1114112;           // 4096
  float* ga2    = ws + 1118208;           // 4096
  // wpk lifetime: k_prep(write) -> k_seq(read); gh written later by k_gatproj.
  ushort_t* wpk = (ushort_t*)gh;          // 49152 bf16 = 96KB < 2MB gh region

  k_prep<<<dim3(192), dim3(256), 0, stream>>>(inw, wpk);
  k_seq<<<dim3(B_ * N_), dim3(512), 0, stream>>>(
      x, pw, pb, inb, ow, ob, l1g, l1b, w1, b1, w2, b2, l2g, l2b, wpk,
      out_tatt, t_repr);
  k_static<<<dim3(256), dim3(256), 0, stream>>>(xst, stw, stb, s_repr);
  k_gatproj<<<dim3(B_ * N_), dim3(128), 0, stream>>>(
      t_repr, s_repr, gatw, gata, gh, ga1, ga2);
  k_gat<<<dim3(B_ * N_), dim3(256), 0, stream>>>(
      adj, gh, ga1, ga2, t_repr, s_repr, fw, fb,
      regw, regb, rkw, rkb, wnw, wnb,
      out_alpha, out_reg, out_risk, out_warn);
}

// Round 12
// 1247.481 us; speedup vs baseline: 1.7816x; 1.7816x over previous
//
#include <hip/hip_runtime.h>

// DustRiskFormer: B=8 T=48 N=512 F=16 S=12 H=128 NH=8 HZ=6 NC=3
// All float tensors f32; adj int32.
// Outputs (f32, concat flat): reg[8,512,6] risk[8,512,6,3] warn[8,512,6]
//                             t_attn[4096,48,48] alpha[8,512,512]
// R7: t_repr = h[:, -1] -> only ROW 47 of out-proj/LN1/FFN/LN2 matters.
// R8: bf16 q/k/v (LDS 53KB); tatt overlays dead hb; row-47 tail.
// R11: FFN residual rebased on ln1v (reference: LN2(ln1v + ffn)).
// R12 FIX: R11 run spilled sc[48]+qv[16] to scratch (VGPR 64, +2.9GB HBM
//     round-trip, VALUBusy 9%). Phase 5 now lane=KEY (kv[16] persistent,
//     q broadcast per row, shfl max/sum) -> no register array; bounds (512,2).

#define B_ 8
#define T_ 48
#define N_ 512
#define F_ 16
#define S_ 12
#define H_ 128
#define NH_ 8
#define HD_ 16

typedef unsigned short ushort_t;
typedef short bf16x8 __attribute__((ext_vector_type(8)));
typedef float f32x4 __attribute__((ext_vector_type(4)));

__device__ __forceinline__ ushort_t f2us(float f) {
  union { float f; unsigned int i; } v; v.f = f;
  unsigned int r = v.i + 0x7FFFu + ((v.i >> 16) & 1u);   // RNE
  return (ushort_t)(r >> 16);
}
__device__ __forceinline__ unsigned int pk2(float a, float b) {
  return (unsigned int)f2us(a) | ((unsigned int)f2us(b) << 16);
}
__device__ __forceinline__ float lo2f(unsigned int u) {
  union { unsigned int i; float f; } v; v.i = u << 16; return v.f;
}
__device__ __forceinline__ float hi2f(unsigned int u) {
  union { unsigned int i; float f; } v; v.i = u & 0xffff0000u; return v.f;
}
__device__ __forceinline__ float us2f(ushort_t u) {
  union { unsigned int i; float f; } v; v.i = ((unsigned int)u) << 16; return v.f;
}
__device__ __forceinline__ float dot128(const float* __restrict__ a,
                                        const float* __restrict__ w) {
  float s = 0.f;
  #pragma unroll 8
  for (int c = 0; c < 32; ++c) {
    float4 av = *(const float4*)(a + 4 * c);
    float4 wv = *(const float4*)(w + 4 * c);
    s += av.x * wv.x + av.y * wv.y + av.z * wv.z + av.w * wv.w;
  }
  return s;
}

#define MFMA16(a, b, c) __builtin_amdgcn_mfma_f32_16x16x32_bf16(a, b, c, 0, 0, 0)

// -------- weight pre-pack (in_w only): f32 -> bf16, MFMA A-fragment order ----
// lane l holds row mt*16+(l&15), k = ks*32+(l>>4)*8+j ; packed[((mt*4+ks)*64+l)*8+j]
__global__ __launch_bounds__(256)
void k_prep(const float* __restrict__ inw, ushort_t* __restrict__ wp)
{
  int i = blockIdx.x * 256 + threadIdx.x;     // 49152 total
  int j    = i & 7;
  int lane = (i >> 3) & 63;
  int tile = i >> 9;
  int mt   = tile >> 2, ks = tile & 3;
  int row  = mt * 16 + (lane & 15);
  int k    = ks * 32 + ((lane >> 4) & 3) * 8 + j;
  wp[i] = f2us(inw[(size_t)row * H_ + k]);
}

struct alignas(16) SmemA {
  union { ushort_t hb[T_][H_]; float tatt[T_][49]; } hu;   // 12.3KB (disjoint lifetimes)
  union { struct { ushort_t q[T_][H_], k[T_][H_], v[T_][H_]; } a;
          float xs[T_][F_]; } u;                            // 36.9KB
  float p47[NH_][T_];   // head-probs for row 47 (PV input)
  float h47[H_];        // residual row 47
  float attn47[H_];
  float ln1v[H_];
  float g47[2 * H_];
};                      // ~53.2KB -> 2-3 blocks/CU

__global__ __launch_bounds__(512, 2)
void k_seq(const float* __restrict__ x,
           const float* __restrict__ pw,  const float* __restrict__ pb,
           const float* __restrict__ in_b,
           const float* __restrict__ ow,  const float* __restrict__ ob,
           const float* __restrict__ l1g, const float* __restrict__ l1b,
           const float* __restrict__ w1,  const float* __restrict__ b1,
           const float* __restrict__ w2,  const float* __restrict__ b2,
           const float* __restrict__ l2g, const float* __restrict__ l2b,
           const ushort_t* __restrict__ wpk,
           float* __restrict__ out_tatt, float* __restrict__ t_repr)
{
  __shared__ SmemA sm;
  const int seq = blockIdx.x;
  const int b = seq >> 9, n = seq & (N_ - 1);
  const int tid = threadIdx.x;
  const int wv = tid >> 6, ln = tid & 63;
  const int lg = ln >> 4, lr = ln & 15;

  // ---- 1. load x[b,:,n,:] ----
  for (int i = tid; i < T_ * F_; i += 512) {
    int t = i >> 4, f = i & 15;
    sm.u.xs[t][f] = x[((size_t)(b * T_ + t) * N_ + n) * F_ + f];
  }
  __syncthreads();

  // ---- 2. proj: hb = bf16(xs @ pw^T + pb), swizzled; row 47 also f32 ----
  for (int i = tid; i < T_ * 64; i += 512) {     // 6 iters
    int t = i >> 6, hp = (i & 63) * 2;
    float s0 = pb[hp], s1 = pb[hp + 1];
    const float* w0 = pw + hp * F_;
    const float* w1r = w0 + F_;
    #pragma unroll
    for (int f = 0; f < F_; ++f) {
      float xv = sm.u.xs[t][f];
      s0 += xv * w0[f]; s1 += xv * w1r[f];
    }
    *(unsigned int*)((char*)sm.hu.hb + ((t * 256 + hp * 2) ^ ((t & 7) << 4))) = pk2(s0, s1);
    if (t == T_ - 1) { sm.h47[hp] = s0; sm.h47[hp + 1] = s1; }
  }
  __syncthreads();

  // ---- 3. qkv MFMA: [384 out] x [48 t], K=128; out -> bf16 q/k/v swizzled ----
  {
    f32x4 acc[3][3];
    #pragma unroll
    for (int i = 0; i < 3; ++i)
      #pragma unroll
      for (int j = 0; j < 3; ++j) acc[i][j] = (f32x4){0.f, 0.f, 0.f, 0.f};
    #pragma unroll
    for (int ks = 0; ks < 4; ++ks) {
      bf16x8 Af[3], Bf[3];
      #pragma unroll
      for (int i = 0; i < 3; ++i) {
        int mt = wv * 3 + i;
        Af[i] = *(const bf16x8*)(wpk + (size_t)((mt * 4 + ks) * 64 + ln) * 8);
        int row = i * 16 + lr;
        Bf[i] = *(const bf16x8*)((const char*)sm.hu.hb +
                 ((row * 256 + ks * 64 + lg * 16) ^ ((row & 7) << 4)));
      }
      #pragma unroll
      for (int i = 0; i < 3; ++i)
        #pragma unroll
        for (int j = 0; j < 3; ++j) acc[i][j] = MFMA16(Af[i], Bf[j], acc[i][j]);
    }
    #pragma unroll
    for (int i = 0; i < 3; ++i) {
      int hh0 = (wv * 3 + i) * 16 + lg * 4;       // 0..383
      float4 bias = *(const float4*)(in_b + hh0);
      #pragma unroll
      for (int j = 0; j < 3; ++j) {
        int t = j * 16 + lr;
        float o0 = acc[i][j].x + bias.x, o1 = acc[i][j].y + bias.y;
        float o2 = acc[i][j].z + bias.z, o3 = acc[i][j].w + bias.w;
        ushort_t* buf; int hl;
        if (hh0 < 128)      { buf = &sm.u.a.q[0][0]; hl = hh0;
                              o0 *= 0.25f; o1 *= 0.25f; o2 *= 0.25f; o3 *= 0.25f; }
        else if (hh0 < 256) { buf = &sm.u.a.k[0][0]; hl = hh0 - 128; }
        else                { buf = &sm.u.a.v[0][0]; hl = hh0 - 256; }
        *(uint2*)((char*)buf + ((t * 256 + hl * 2) ^ ((t & 7) << 4))) =
            make_uint2(pk2(o0, o1), pk2(o2, o3));
      }
    }
  }
  __syncthreads();

  // ---- 4. zero tatt (hb now dead) ----
  for (int i = tid; i < T_ * 49; i += 512) (&sm.hu.tatt[0][0])[i] = 0.f;
  __syncthreads();

  // ---- 5. attention: wave = head, lane = KEY index; query rows serial ----
  // (R12: no per-lane score array -> no spill. kv[16] persistent; q row is a
  //  2x b128 broadcast read; max/sum via 6-step shfl over the full wave.)
  {
    const char* kb = (const char*)sm.u.a.k;
    const char* qb = (const char*)sm.u.a.q;
    float kv[16];
    if (ln < T_) {
      uint4 ka = *(const uint4*)(kb + ((ln * 256 + wv * 32) ^ ((ln & 7) << 4)));
      uint4 kc = *(const uint4*)(kb + ((ln * 256 + wv * 32 + 16) ^ ((ln & 7) << 4)));
      kv[0] = lo2f(ka.x);  kv[1] = hi2f(ka.x);  kv[2] = lo2f(ka.y);  kv[3] = hi2f(ka.y);
      kv[4] = lo2f(ka.z);  kv[5] = hi2f(ka.z);  kv[6] = lo2f(ka.w);  kv[7] = hi2f(ka.w);
      kv[8] = lo2f(kc.x);  kv[9] = hi2f(kc.x);  kv[10] = lo2f(kc.y); kv[11] = hi2f(kc.y);
      kv[12] = lo2f(kc.z); kv[13] = hi2f(kc.z); kv[14] = lo2f(kc.w); kv[15] = hi2f(kc.w);
    } else {
      #pragma unroll
      for (int d = 0; d < 16; ++d) kv[d] = 0.f;
    }
    for (int r = 0; r < T_; ++r) {
      uint4 qa = *(const uint4*)(qb + ((r * 256 + wv * 32) ^ ((r & 7) << 4)));
      uint4 qc = *(const uint4*)(qb + ((r * 256 + wv * 32 + 16) ^ ((r & 7) << 4)));
      float s = kv[0] * lo2f(qa.x) + kv[1] * hi2f(qa.x) + kv[2] * lo2f(qa.y) + kv[3] * hi2f(qa.y)
              + kv[4] * lo2f(qa.z) + kv[5] * hi2f(qa.z) + kv[6] * lo2f(qa.w) + kv[7] * hi2f(qa.w)
              + kv[8] * lo2f(qc.x) + kv[9] * hi2f(qc.x) + kv[10] * lo2f(qc.y) + kv[11] * hi2f(qc.y)
              + kv[12] * lo2f(qc.z) + kv[13] * hi2f(qc.z) + kv[14] * lo2f(qc.w) + kv[15] * hi2f(qc.w);
      if (ln >= T_) s = -1e30f;
      float m = s;
      #pragma unroll
      for (int off = 32; off; off >>= 1) m = fmaxf(m, __shfl_xor(m, off, 64));
      float p = __expf(s - m);
      if (ln >= T_) p = 0.f;
      float sum = p;
      #pragma unroll
      for (int off = 32; off; off >>= 1) sum += __shfl_xor(sum, off, 64);
      float pn = p / sum;
      if (ln < T_) {
        atomicAdd(&sm.hu.tatt[r][ln], pn * 0.125f);
        if (r == T_ - 1) sm.p47[wv][ln] = pn;
      }
    }
  }
  __syncthreads();

  // ---- 6. tatt writeout + PV(row 47) -> attn47 ----
  for (int i = tid; i < T_ * T_; i += 512) {
    int r = i / T_, k = i - r * T_;
    out_tatt[(size_t)seq * T_ * T_ + i] = sm.hu.tatt[r][k];
  }
  {
    // 512 thr: head=wv, c=ln>>2, ks=ln&3; 12 k each; shfl-reduce 4 partials
    int c = ln >> 2, ks = ln & 3;
    const char* vb = (const char*)sm.u.a.v;
    float a = 0.f;
    for (int kk = 0; kk < 12; ++kk) {
      int k = ks * 12 + kk;
      float p = sm.p47[wv][k];
      ushort_t vv = *(const ushort_t*)(vb + ((k * 256 + (wv * 16 + c) * 2) ^ ((k & 7) << 4)));
      a += p * us2f(vv);
    }
    a += __shfl_xor(a, 1, 64);
    a += __shfl_xor(a, 2, 64);
    if (ks == 0) sm.attn47[wv * 16 + c] = a;
  }
  __syncthreads();

  // ---- 7. out-proj row 47: h47 += attn47 @ ow^T + ob  (h47 = h1 + attn) ----
  {
    int o = tid >> 2, ks = tid & 3;
    const float* wr = ow + (size_t)o * H_ + ks * 32;
    const float* ar = sm.attn47 + ks * 32;
    float s = 0.f;
    #pragma unroll
    for (int c = 0; c < 8; ++c) {
      float4 av = *(const float4*)(ar + 4 * c);
      float4 wvv = *(const float4*)(wr + 4 * c);
      s += av.x * wvv.x + av.y * wvv.y + av.z * wvv.z + av.w * wvv.w;
    }
    s += __shfl_xor(s, 1, 64);
    s += __shfl_xor(s, 2, 64);
    if (ks == 0) sm.h47[o] += s + ob[o];
  }
  __syncthreads();

  // ---- 8. LN1 row 47 (wave 0) -> ln1v ----
  if (tid < 64) {
    float v0 = sm.h47[2 * tid], v1 = sm.h47[2 * tid + 1];
    float s = v0 + v1;
    #pragma unroll
    for (int off = 32; off; off >>= 1) s += __shfl_xor(s, off, 64);
    float mean = s * (1.f / H_);
    float d0 = v0 - mean, d1 = v1 - mean;
    float q = d0 * d0 + d1 * d1;
    #pragma unroll
    for (int off = 32; off; off >>= 1) q += __shfl_xor(q, off, 64);
    float rstd = rsqrtf(q * (1.f / H_) + 1e-5f);
    sm.ln1v[2 * tid]     = d0 * rstd * l1g[2 * tid]     + l1b[2 * tid];
    sm.ln1v[2 * tid + 1] = d1 * rstd * l1g[2 * tid + 1] + l1b[2 * tid + 1];
  }
  __syncthreads();

  // ---- 9. FFN1 row 47: g47 = gelu(ln1v @ w1^T + b1) ----
  {
    int o = tid >> 1, ks = tid & 1;
    const float* wr = w1 + (size_t)o * H_ + ks * 64;
    const float* ar = sm.ln1v + ks * 64;
    float s = 0.f;
    #pragma unroll
    for (int c = 0; c < 16; ++c) {
      float4 av = *(const float4*)(ar + 4 * c);
      float4 wvv = *(const float4*)(wr + 4 * c);
      s += av.x * wvv.x + av.y * wvv.y + av.z * wvv.z + av.w * wvv.w;
    }
    s += __shfl_xor(s, 1, 64);
    if (ks == 0) {
      float g = s + b1[o];
      sm.g47[o] = 0.5f * g * (1.f + erff(g * 0.70710678118f));
    }
  }
  __syncthreads();

  // ---- 10. FFN2 row 47: h47 = ln1v + g47 @ w2^T + b2  (residual = ln1v) ----
  {
    int o = tid >> 2, ks = tid & 3;
    const float* wr = w2 + (size_t)o * 2 * H_ + ks * 64;
    const float* ar = sm.g47 + ks * 64;
    float s = 0.f;
    #pragma unroll
    for (int c = 0; c < 16; ++c) {
      float4 av = *(const float4*)(ar + 4 * c);
      float4 wvv = *(const float4*)(wr + 4 * c);
      s += av.x * wvv.x + av.y * wvv.y + av.z * wvv.z + av.w * wvv.w;
    }
    s += __shfl_xor(s, 1, 64);
    s += __shfl_xor(s, 2, 64);
    if (ks == 0) sm.h47[o] = sm.ln1v[o] + s + b2[o];
  }
  __syncthreads();

  // ---- 11. LN2 row 47 (wave 0) -> t_repr ----
  if (tid < 64) {
    float v0 = sm.h47[2 * tid], v1 = sm.h47[2 * tid + 1];
    float s = v0 + v1;
    #pragma unroll
    for (int off = 32; off; off >>= 1) s += __shfl_xor(s, off, 64);
    float mean = s * (1.f / H_);
    float d0 = v0 - mean, d1 = v1 - mean;
    float q = d0 * d0 + d1 * d1;
    #pragma unroll
    for (int off = 32; off; off >>= 1) q += __shfl_xor(q, off, 64);
    float rstd = rsqrtf(q * (1.f / H_) + 1e-5f);
    t_repr[(size_t)seq * H_ + 2 * tid]     = d0 * rstd * l2g[2 * tid]     + l2b[2 * tid];
    t_repr[(size_t)seq * H_ + 2 * tid + 1] = d1 * rstd * l2g[2 * tid + 1] + l2b[2 * tid + 1];
  }
}

// s_repr[n][hh] = relu(x_static[n] . stat_w[hh] + stat_b[hh])
__global__ __launch_bounds__(256)
void k_static(const float* __restrict__ xst, const float* __restrict__ sw,
              const float* __restrict__ sb, float* __restrict__ s_repr)
{
  int idx = blockIdx.x * 256 + threadIdx.x;   // 512*128
  int n = idx >> 7, hh = idx & 127;
  float s = sb[hh];
  #pragma unroll
  for (int c = 0; c < S_; ++c) s += xst[n * S_ + c] * sw[hh * S_ + c];
  s_repr[idx] = fmaxf(s, 0.f);
}

// gh[b,n,:] = node @ gat_w^T ; ga1/ga2 = gh . a1 / a2
__global__ __launch_bounds__(128)
void k_gatproj(const float* __restrict__ t_repr, const float* __restrict__ s_repr,
               const float* __restrict__ gat_w, const float* __restrict__ gat_a,
               float* __restrict__ gh, float* __restrict__ ga1, float* __restrict__ ga2)
{
  int bi = blockIdx.x;            // b*512+n
  int n = bi & (N_ - 1);
  int hh = threadIdx.x;
  const float* wr = gat_w + hh * 2 * H_;
  float s = dot128(t_repr + (size_t)bi * H_, wr) +
            dot128(s_repr + (size_t)n * H_, wr + H_);
  gh[(size_t)bi * H_ + hh] = s;
  float c1 = s * gat_a[hh];
  float c2 = s * gat_a[H_ + hh];
  #pragma unroll
  for (int off = 32; off; off >>= 1) {
    c1 += __shfl_xor(c1, off, 64);
    c2 += __shfl_xor(c2, off, 64);
  }
  __shared__ float r1[2], r2[2];
  int w = hh >> 6;
  if ((hh & 63) == 0) { r1[w] = c1; r2[w] = c2; }
  __syncthreads();
  if (hh == 0) { ga1[bi] = r1[0] + r1[1]; ga2[bi] = r2[0] + r2[1]; }
}

// per (b,i): e-row -> softmax -> alpha out; g_repr; fused; heads
__global__ __launch_bounds__(256)
void k_gat(const int* __restrict__ adj, const float* __restrict__ gh,
           const float* __restrict__ ga1, const float* __restrict__ ga2,
           const float* __restrict__ t_repr, const float* __restrict__ s_repr,
           const float* __restrict__ fw, const float* __restrict__ fb,
           const float* __restrict__ regw, const float* __restrict__ regb,
           const float* __restrict__ riskw, const float* __restrict__ riskb,
           const float* __restrict__ warnw, const float* __restrict__ warnb,
           float* __restrict__ out_alpha, float* __restrict__ out_reg,
           float* __restrict__ out_risk, float* __restrict__ out_warn)
{
  const int row = blockIdx.x;     // b*512 + i
  const int bb = row >> 9, i = row & (N_ - 1);
  const int tid = threadIdx.x;
  __shared__ float ev[N_];
  alignas(16) __shared__ float av[3 * H_];   // [t_repr row | s_repr row | g_repr]
  __shared__ float part[256];
  alignas(16) __shared__ float fus[H_];
  __shared__ float red[4];

  const float g1 = ga1[row];
  const float* g2 = ga2 + (size_t)bb * N_;
  float lmax = -1e30f;
  for (int j = tid; j < N_; j += 256) {
    float e = g1 + g2[j];
    e = e > 0.f ? e : 0.2f * e;               // leaky_relu(0.2)
    if (adj[i * N_ + j] == 0) e = -1e30f;     // mask
    ev[j] = e; lmax = fmaxf(lmax, e);
  }
  #pragma unroll
  for (int off = 32; off; off >>= 1) lmax = fmaxf(lmax, __shfl_xor(lmax, off, 64));
  if ((tid & 63) == 0) red[tid >> 6] = lmax;
  __syncthreads();
  const float m = fmaxf(fmaxf(red[0], red[1]), fmaxf(red[2], red[3]));
  float lsum = 0.f;
  for (int j = tid; j < N_; j += 256) {
    float p = __expf(ev[j] - m);
    ev[j] = p; lsum += p;
  }
  #pragma unroll
  for (int off = 32; off; off >>= 1) lsum += __shfl_xor(lsum, off, 64);
  __syncthreads();                             // all have read red (max)
  if ((tid & 63) == 0) red[tid >> 6] = lsum;
  __syncthreads();
  const float inv = 1.f / (red[0] + red[1] + red[2] + red[3]);
  for (int j = tid; j < N_; j += 256) {
    float a = ev[j] * inv;
    ev[j] = a;
    out_alpha[(size_t)row * N_ + j] = a;
  }
  // stage av[0:256] = [t_repr row | s_repr row]
  av[tid] = (tid < H_) ? t_repr[(size_t)row * H_ + tid]
                       : s_repr[(size_t)i * H_ + (tid - H_)];
  __syncthreads();

  // g_repr: 256 thr (hh x K-half), then halves reduce
  {
    int hh = tid & 127, half = tid >> 7;
    const float* ghb = gh + ((size_t)bb * N_ + half * 256) * H_ + hh;
    float acc = 0.f;
    for (int j = 0; j < 256; ++j) acc += ev[half * 256 + j] * ghb[(size_t)j * H_];
    part[tid] = acc;
  }
  __syncthreads();
  if (tid < H_) av[2 * H_ + tid] = part[tid] + part[H_ + tid];
  __syncthreads();

  // fused: 256 thr (hh x K-half of 192), then reduce + relu
  {
    int hh = tid & 127, half = tid >> 7;
    const float* wr = fw + (size_t)hh * 3 * H_ + half * 192;
    const float* ar = av + half * 192;
    float s = 0.f;
    #pragma unroll 8
    for (int c = 0; c < 48; ++c) {
      float4 avv = *(const float4*)(ar + 4 * c);
      float4 wvv = *(const float4*)(wr + 4 * c);
      s += avv.x * wvv.x + avv.y * wvv.y + avv.z * wvv.z + avv.w * wvv.w;
    }
    part[tid] = s;
  }
  __syncthreads();
  if (tid < H_) fus[tid] = fmaxf(part[tid] + part[H_ + tid] + fb[tid], 0.f);
  __syncthreads();

  if (tid < 30) {                              // heads: 6 reg, 18 risk, 6 warn
    const float *wp, *bp; float* op; int o;
    if (tid < 6)       { o = tid;      wp = regw  + o * H_; bp = regb  + o; op = out_reg  + (size_t)row * 6  + o; }
    else if (tid < 24) { o = tid - 6;  wp = riskw + o * H_; bp = riskb + o; op = out_risk + (size_t)row * 18 + o; }
    else               { o = tid - 24; wp = warnw + o * H_; bp = warnb + o; op = out_warn + (size_t)row * 6  + o; }
    float s = *bp + dot128(fus, wp);
    *op = s;
  }
}

extern "C" void kernel_launch(void* const* d_in, const int* in_sizes, int n_in,
                              void* d_out, int out_size, void* d_ws, size_t ws_size,
                              hipStream_t stream)
{
  const float* x    = (const float*)d_in[0];
  const float* xst  = (const float*)d_in[1];
  const int*   adj  = (const int*)d_in[2];
  const float* pw   = (const float*)d_in[3];
  const float* pb   = (const float*)d_in[4];
  const float* inw  = (const float*)d_in[5];
  const float* inb  = (const float*)d_in[6];
  const float* ow   = (const float*)d_in[7];
  const float* ob   = (const float*)d_in[8];
  const float* l1g  = (const float*)d_in[9];
  const float* l1b  = (const float*)d_in[10];
  const float* w1   = (const float*)d_in[11];
  const float* b1   = (const float*)d_in[12];
  const float* w2   = (const float*)d_in[13];
  const float* b2   = (const float*)d_in[14];
  const float* l2g  = (const float*)d_in[15];
  const float* l2b  = (const float*)d_in[16];
  const float* stw  = (const float*)d_in[17];
  const float* stb  = (const float*)d_in[18];
  const float* gatw = (const float*)d_in[19];
  const float* gata = (const float*)d_in[20];
  const float* fw   = (const float*)d_in[21];
  const float* fb   = (const float*)d_in[22];
  const float* regw = (const float*)d_in[23];
  const float* regb = (const float*)d_in[24];
  const float* rkw  = (const float*)d_in[25];
  const float* rkb  = (const float*)d_in[26];
  const float* wnw  = (const float*)d_in[27];
  const float* wnb  = (const float*)d_in[28];

  float* out       = (float*)d_out;
  float* out_reg   = out;                 // 24576
  float* out_risk  = out + 24576;         // 73728
  float* out_warn  = out + 98304;         // 24576
  float* out_tatt  = out + 122880;        // 9437184
  float* out_alpha = out + 9560064;       // 2097152

  float* ws     = (float*)d_ws;           // f32 scratch (4,489,216 B total, proven)
  float* t_repr = ws;                     // 4096*128
  float* s_repr = ws + 524288;            // 512*128
  float* gh     = ws + 589824;            // 4096*128  (wpk aliases the front)
  float* ga1    = ws + 1114112;           // 4096
  float* ga2    = ws + 1118208;           // 4096
  // wpk lifetime: k_prep(write) -> k_seq(read); gh written later by k_gatproj.
  ushort_t* wpk = (ushort_t*)gh;          // 49152 bf16 = 96KB < 2MB gh region

  k_prep<<<dim3(192), dim3(256), 0, stream>>>(inw, wpk);
  k_seq<<<dim3(B_ * N_), dim3(512), 0, stream>>>(
      x, pw, pb, inb, ow, ob, l1g, l1b, w1, b1, w2, b2, l2g, l2b, wpk,
      out_tatt, t_repr);
  k_static<<<dim3(256), dim3(256), 0, stream>>>(xst, stw, stb, s_repr);
  k_gatproj<<<dim3(B_ * N_), dim3(128), 0, stream>>>(
      t_repr, s_repr, gatw, gata, gh, ga1, ga2);
  k_gat<<<dim3(B_ * N_), dim3(256), 0, stream>>>(
      adj, gh, ga1, ga2, t_repr, s_repr, fw, fb,
      regw, regb, rkw, rkb, wnw, wnb,
      out_alpha, out_reg, out_risk, out_warn);
}